// Round 1
// baseline (180.022 us; speedup 1.0000x reference)
//
#include <hip/hip_runtime.h>
#include <hip/hip_bf16.h>

// Shapes (hardcoded per reference): B=4, T=4096, E=1024, H=64
// q,k,v stored bf16 in d_ws; attention flash-style, fp32 accumulation.

typedef __attribute__((ext_vector_type(8))) short short8;   // 8 bf16 (4 VGPR) MFMA frag
typedef __attribute__((ext_vector_type(4))) short short4v;
typedef __attribute__((ext_vector_type(4))) float f32x4;

__device__ inline short f2bf(float f) {
  __hip_bfloat16 h = __float2bfloat16(f);  // RNE
  union { __hip_bfloat16 h; short s; } u; u.h = h; return u.s;
}

#define PROJ_BM 128
#define PROJ_BK 64

// C = x[M=16384,K=1024] @ W[K=1024,N=64], output bf16.
// blockIdx.y selects which of Wk/Wq/Wv.
__global__ __launch_bounds__(256) void proj_kernel(
    const float* __restrict__ x,
    const float* __restrict__ Wk, const float* __restrict__ Wq, const float* __restrict__ Wv,
    short* __restrict__ kout, short* __restrict__ qout, short* __restrict__ vout)
{
  const float* W; short* out;
  if (blockIdx.y == 0)      { W = Wk; out = kout; }
  else if (blockIdx.y == 1) { W = Wq; out = qout; }
  else                      { W = Wv; out = vout; }

  // +8 short pad => row stride 144B, breaks same-bank stride for ds_read_b128
  __shared__ __align__(16) short xl[PROJ_BM][PROJ_BK + 8];
  __shared__ __align__(16) short wl[64][PROJ_BK + 8];   // W^T: [col][k]

  const int tid = threadIdx.x;
  const int w   = tid >> 6;
  const int lane = tid & 63;
  const int lr  = lane & 15;   // MFMA row/col index
  const int lg  = lane >> 4;   // MFMA k-group
  const int rowbase = blockIdx.x * PROJ_BM;

  f32x4 acc[2][4];
  for (int i = 0; i < 2; ++i)
    for (int j = 0; j < 4; ++j)
      acc[i][j] = (f32x4){0.f, 0.f, 0.f, 0.f};

  for (int kb = 0; kb < 1024; kb += PROJ_BK) {
    __syncthreads();
    // stage x tile 128x64 fp32 -> bf16 LDS (coalesced float4 loads)
    for (int p = 0; p < 8; ++p) {
      int idx4 = p * 256 + tid;
      int r  = idx4 >> 4;            // 16 float4 per row
      int c  = (idx4 & 15) << 2;     // float col
      float4 vv = *reinterpret_cast<const float4*>(&x[(size_t)(rowbase + r) * 1024 + kb + c]);
      short4v sv;
      sv.x = f2bf(vv.x); sv.y = f2bf(vv.y); sv.z = f2bf(vv.z); sv.w = f2bf(vv.w);
      *reinterpret_cast<short4v*>(&xl[r][c]) = sv;
    }
    // stage W tile 64x64 transposed: wl[c][k]
    for (int p = 0; p < 4; ++p) {
      int idx4 = p * 256 + tid;
      int kr = idx4 >> 4;
      int c  = (idx4 & 15) << 2;
      float4 vv = *reinterpret_cast<const float4*>(&W[(size_t)(kb + kr) * 64 + c]);
      wl[c + 0][kr] = f2bf(vv.x);
      wl[c + 1][kr] = f2bf(vv.y);
      wl[c + 2][kr] = f2bf(vv.z);
      wl[c + 3][kr] = f2bf(vv.w);
    }
    __syncthreads();

    for (int ks = 0; ks < 2; ++ks) {
      short8 a[2], b[4];
      for (int rt = 0; rt < 2; ++rt)
        a[rt] = *reinterpret_cast<const short8*>(&xl[32 * w + 16 * rt + lr][ks * 32 + lg * 8]);
      for (int ct = 0; ct < 4; ++ct)
        b[ct] = *reinterpret_cast<const short8*>(&wl[16 * ct + lr][ks * 32 + lg * 8]);
      for (int rt = 0; rt < 2; ++rt)
        for (int ct = 0; ct < 4; ++ct)
          acc[rt][ct] = __builtin_amdgcn_mfma_f32_16x16x32_bf16(a[rt], b[ct], acc[rt][ct], 0, 0, 0);
    }
  }

  // epilogue: D layout col=lane&15, row=(lane>>4)*4+j
  for (int rt = 0; rt < 2; ++rt)
    for (int ct = 0; ct < 4; ++ct)
      for (int j = 0; j < 4; ++j) {
        int grow = rowbase + 32 * w + 16 * rt + lg * 4 + j;
        out[(size_t)grow * 64 + 16 * ct + lr] = f2bf(acc[rt][ct][j]);
      }
}

// Flash attention fwd: 1 block = 64 q rows (4 waves x 16), KBLK=64, no mask.
__global__ __launch_bounds__(256) void attn_kernel(
    const short* __restrict__ qm, const short* __restrict__ km, const short* __restrict__ vm,
    float* __restrict__ out)
{
  const int b  = blockIdx.x >> 6;   // T/64 = 64 q-tiles per batch
  const int qt = blockIdx.x & 63;
  const int tid = threadIdx.x;
  const int w   = tid >> 6;
  const int lane = tid & 63;
  const int lr  = lane & 15;
  const int lg  = lane >> 4;

  const short* qb = qm + ((size_t)b * 4096 + qt * 64) * 64;
  const short* kb = km + (size_t)b * 4096 * 64;
  const short* vb = vm + (size_t)b * 4096 * 64;

  __shared__ __align__(16) short vl[64][72];       // V^T: [d][key], padded
  __shared__ __align__(16) short pl[4][16][72];    // per-wave P: [qrow][key], padded

  // hoist Q fragments (A-operand: row=lr, k=lg*8+j within 32-slice)
  short8 qf[2];
  for (int ks = 0; ks < 2; ++ks)
    qf[ks] = *reinterpret_cast<const short8*>(&qb[(16 * w + lr) * 64 + ks * 32 + lg * 8]);

  float m[4], l[4];
  f32x4 o[4];
  for (int j = 0; j < 4; ++j) { m[j] = -3e38f; l[j] = 0.f; }
  for (int ct = 0; ct < 4; ++ct) o[ct] = (f32x4){0.f, 0.f, 0.f, 0.f};

  const float scale = 0.125f;   // 1/sqrt(64)

  for (int kt = 0; kt < 64; ++kt) {
    __syncthreads();   // protect vl/pl from previous iteration's readers

    // stage V^T tile: vl[d][key] <- v[key][d]
    const short* vt = vb + (size_t)kt * 64 * 64;
    for (int p = 0; p < 4; ++p) {
      int idx4 = p * 256 + tid;
      int key = idx4 >> 4;
      int d0  = (idx4 & 15) << 2;
      short4v vv = *reinterpret_cast<const short4v*>(&vt[key * 64 + d0]);
      vl[d0 + 0][key] = vv.x;
      vl[d0 + 1][key] = vv.y;
      vl[d0 + 2][key] = vv.z;
      vl[d0 + 3][key] = vv.w;
    }

    // S = Q K^T (K fragments straight from global; L2-resident)
    f32x4 s[4];
    for (int ct = 0; ct < 4; ++ct) s[ct] = (f32x4){0.f, 0.f, 0.f, 0.f};
    for (int ks = 0; ks < 2; ++ks)
      for (int ct = 0; ct < 4; ++ct) {
        short8 kf = *reinterpret_cast<const short8*>(
            &kb[((size_t)kt * 64 + 16 * ct + lr) * 64 + ks * 32 + lg * 8]);
        s[ct] = __builtin_amdgcn_mfma_f32_16x16x32_bf16(qf[ks], kf, s[ct], 0, 0, 0);
      }

    // online softmax; lane owns rows r=lg*4+j, cols 16*ct+lr
    for (int j = 0; j < 4; ++j) {
      float mx = fmaxf(fmaxf(s[0][j], s[1][j]), fmaxf(s[2][j], s[3][j]));
      for (int off = 1; off < 16; off <<= 1) mx = fmaxf(mx, __shfl_xor(mx, off));
      mx *= scale;
      float mn    = fmaxf(m[j], mx);
      float alpha = __expf(m[j] - mn);
      m[j] = mn;
      float ps = 0.f;
      for (int ct = 0; ct < 4; ++ct) {
        float p = __expf(s[ct][j] * scale - mn);
        ps += p;
        pl[w][lg * 4 + j][16 * ct + lr] = f2bf(p);
      }
      for (int off = 1; off < 16; off <<= 1) ps += __shfl_xor(ps, off);
      l[j] = l[j] * alpha + ps;
      for (int ct = 0; ct < 4; ++ct) o[ct][j] *= alpha;
    }

    __syncthreads();   // vl + pl writes visible

    // O += P V  (A = P from pl, B = V from vl[d][key] rows)
    for (int ks = 0; ks < 2; ++ks) {
      short8 pf = *reinterpret_cast<const short8*>(&pl[w][lr][ks * 32 + lg * 8]);
      for (int ct = 0; ct < 4; ++ct) {
        short8 vf = *reinterpret_cast<const short8*>(&vl[16 * ct + lr][ks * 32 + lg * 8]);
        o[ct] = __builtin_amdgcn_mfma_f32_16x16x32_bf16(pf, vf, o[ct], 0, 0, 0);
      }
    }
  }

  // epilogue: out fp32, divide by row sum
  float* ob = out + ((size_t)b * 4096 + qt * 64 + 16 * w) * 64;
  for (int j = 0; j < 4; ++j) {
    float inv = 1.f / l[j];
    for (int ct = 0; ct < 4; ++ct)
      ob[(lg * 4 + j) * 64 + 16 * ct + lr] = o[ct][j] * inv;
  }
}

extern "C" void kernel_launch(void* const* d_in, const int* in_sizes, int n_in,
                              void* d_out, int out_size, void* d_ws, size_t ws_size,
                              hipStream_t stream) {
  const float* x  = (const float*)d_in[0];
  const float* Wk = (const float*)d_in[1];
  const float* Wq = (const float*)d_in[2];
  const float* Wv = (const float*)d_in[3];

  const size_t MH = (size_t)16384 * 64;   // B*T*H elements
  short* kmat = (short*)d_ws;
  short* qmat = kmat + MH;
  short* vmat = qmat + MH;

  dim3 gproj(16384 / PROJ_BM, 3);
  proj_kernel<<<gproj, 256, 0, stream>>>(x, Wk, Wq, Wv, kmat, qmat, vmat);

  attn_kernel<<<256, 256, 0, stream>>>(qmat, kmat, vmat, (float*)d_out);
}

// Round 2
// 133.284 us; speedup vs baseline: 1.3507x; 1.3507x over previous
//
#include <hip/hip_runtime.h>
#include <hip/hip_bf16.h>

// Shapes (hardcoded per reference): B=4, T=4096, E=1024, H=64
// q,k,v stored bf16 in d_ws; attention flash-style with KV-split + LSE merge.

typedef __attribute__((ext_vector_type(8))) short short8;   // 8 bf16 (4 VGPR) MFMA frag
typedef __attribute__((ext_vector_type(4))) short short4v;
typedef __attribute__((ext_vector_type(4))) float f32x4;

__device__ inline short f2bf(float f) {
  __hip_bfloat16 h = __float2bfloat16(f);  // RNE
  union { __hip_bfloat16 h; short s; } u; u.h = h; return u.s;
}

#define PROJ_BM 128
#define PROJ_BK 64

// C = x[M=16384,K=1024] @ W[K=1024,N=64], output bf16.
__global__ __launch_bounds__(256) void proj_kernel(
    const float* __restrict__ x,
    const float* __restrict__ Wk, const float* __restrict__ Wq, const float* __restrict__ Wv,
    short* __restrict__ kout, short* __restrict__ qout, short* __restrict__ vout)
{
  const float* W; short* out;
  if (blockIdx.y == 0)      { W = Wk; out = kout; }
  else if (blockIdx.y == 1) { W = Wq; out = qout; }
  else                      { W = Wv; out = vout; }

  __shared__ __align__(16) short xl[PROJ_BM][PROJ_BK + 8];
  __shared__ __align__(16) short wl[64][PROJ_BK + 8];   // W^T: [col][k]

  const int tid = threadIdx.x;
  const int w   = tid >> 6;
  const int lane = tid & 63;
  const int lr  = lane & 15;
  const int lg  = lane >> 4;
  const int rowbase = blockIdx.x * PROJ_BM;

  f32x4 acc[2][4];
  for (int i = 0; i < 2; ++i)
    for (int j = 0; j < 4; ++j)
      acc[i][j] = (f32x4){0.f, 0.f, 0.f, 0.f};

  for (int kb = 0; kb < 1024; kb += PROJ_BK) {
    __syncthreads();
    for (int p = 0; p < 8; ++p) {
      int idx4 = p * 256 + tid;
      int r  = idx4 >> 4;
      int c  = (idx4 & 15) << 2;
      float4 vv = *reinterpret_cast<const float4*>(&x[(size_t)(rowbase + r) * 1024 + kb + c]);
      short4v sv;
      sv.x = f2bf(vv.x); sv.y = f2bf(vv.y); sv.z = f2bf(vv.z); sv.w = f2bf(vv.w);
      *reinterpret_cast<short4v*>(&xl[r][c]) = sv;
    }
    for (int p = 0; p < 4; ++p) {
      int idx4 = p * 256 + tid;
      int kr = idx4 >> 4;
      int c  = (idx4 & 15) << 2;
      float4 vv = *reinterpret_cast<const float4*>(&W[(size_t)(kb + kr) * 64 + c]);
      wl[c + 0][kr] = f2bf(vv.x);
      wl[c + 1][kr] = f2bf(vv.y);
      wl[c + 2][kr] = f2bf(vv.z);
      wl[c + 3][kr] = f2bf(vv.w);
    }
    __syncthreads();

    for (int ks = 0; ks < 2; ++ks) {
      short8 a[2], b[4];
      for (int rt = 0; rt < 2; ++rt)
        a[rt] = *reinterpret_cast<const short8*>(&xl[32 * w + 16 * rt + lr][ks * 32 + lg * 8]);
      for (int ct = 0; ct < 4; ++ct)
        b[ct] = *reinterpret_cast<const short8*>(&wl[16 * ct + lr][ks * 32 + lg * 8]);
      for (int rt = 0; rt < 2; ++rt)
        for (int ct = 0; ct < 4; ++ct)
          acc[rt][ct] = __builtin_amdgcn_mfma_f32_16x16x32_bf16(a[rt], b[ct], acc[rt][ct], 0, 0, 0);
    }
  }

  for (int rt = 0; rt < 2; ++rt)
    for (int ct = 0; ct < 4; ++ct)
      for (int j = 0; j < 4; ++j) {
        int grow = rowbase + 32 * w + 16 * rt + lg * 4 + j;
        out[(size_t)grow * 64 + 16 * ct + lr] = f2bf(acc[rt][ct][j]);
      }
}

// KV-split flash attention: one block = 64 q rows x one KV chunk.
// Writes unnormalized o-accumulator + per-row (m, l) partials.
__global__ __launch_bounds__(256) void attn_split_kernel(
    const short* __restrict__ qm, const short* __restrict__ km, const short* __restrict__ vm,
    float* __restrict__ opart, float* __restrict__ mpart, float* __restrict__ lpart,
    int S, int chunkTiles)
{
  const int qidx  = blockIdx.x / S;      // 0..255
  const int split = blockIdx.x % S;
  const int b  = qidx >> 6;
  const int qt = qidx & 63;
  const int tid = threadIdx.x;
  const int w   = tid >> 6;
  const int lane = tid & 63;
  const int lr  = lane & 15;
  const int lg  = lane >> 4;

  const short* qb = qm + ((size_t)b * 4096 + qt * 64) * 64;
  const short* kb = km + (size_t)b * 4096 * 64;
  const short* vb = vm + (size_t)b * 4096 * 64;

  __shared__ __align__(16) short vl[64][72];       // V^T: [d][key], padded
  __shared__ __align__(16) short pl[4][16][72];    // per-wave P: [qrow][key], padded

  short8 qf[2];
  for (int ks = 0; ks < 2; ++ks)
    qf[ks] = *reinterpret_cast<const short8*>(&qb[(16 * w + lr) * 64 + ks * 32 + lg * 8]);

  float m[4], l[4];
  f32x4 o[4];
  for (int j = 0; j < 4; ++j) { m[j] = -3e38f; l[j] = 0.f; }
  for (int ct = 0; ct < 4; ++ct) o[ct] = (f32x4){0.f, 0.f, 0.f, 0.f};

  const float scale = 0.125f;   // 1/sqrt(64)
  const int kt0 = split * chunkTiles;

  for (int kt = kt0; kt < kt0 + chunkTiles; ++kt) {
    __syncthreads();

    const short* vt = vb + (size_t)kt * 64 * 64;
    for (int p = 0; p < 4; ++p) {
      int idx4 = p * 256 + tid;
      int key = idx4 >> 4;
      int d0  = (idx4 & 15) << 2;
      short4v vv = *reinterpret_cast<const short4v*>(&vt[key * 64 + d0]);
      vl[d0 + 0][key] = vv.x;
      vl[d0 + 1][key] = vv.y;
      vl[d0 + 2][key] = vv.z;
      vl[d0 + 3][key] = vv.w;
    }

    f32x4 s[4];
    for (int ct = 0; ct < 4; ++ct) s[ct] = (f32x4){0.f, 0.f, 0.f, 0.f};
    for (int ks = 0; ks < 2; ++ks)
      for (int ct = 0; ct < 4; ++ct) {
        short8 kf = *reinterpret_cast<const short8*>(
            &kb[((size_t)kt * 64 + 16 * ct + lr) * 64 + ks * 32 + lg * 8]);
        s[ct] = __builtin_amdgcn_mfma_f32_16x16x32_bf16(qf[ks], kf, s[ct], 0, 0, 0);
      }

    for (int j = 0; j < 4; ++j) {
      float mx = fmaxf(fmaxf(s[0][j], s[1][j]), fmaxf(s[2][j], s[3][j]));
      for (int off = 1; off < 16; off <<= 1) mx = fmaxf(mx, __shfl_xor(mx, off));
      mx *= scale;
      float mn    = fmaxf(m[j], mx);
      float alpha = __expf(m[j] - mn);
      m[j] = mn;
      float ps = 0.f;
      for (int ct = 0; ct < 4; ++ct) {
        float p = __expf(s[ct][j] * scale - mn);
        ps += p;
        pl[w][lg * 4 + j][16 * ct + lr] = f2bf(p);
      }
      for (int off = 1; off < 16; off <<= 1) ps += __shfl_xor(ps, off);
      l[j] = l[j] * alpha + ps;
      for (int ct = 0; ct < 4; ++ct) o[ct][j] *= alpha;
    }

    __syncthreads();

    for (int ks = 0; ks < 2; ++ks) {
      short8 pf = *reinterpret_cast<const short8*>(&pl[w][lr][ks * 32 + lg * 8]);
      for (int ct = 0; ct < 4; ++ct) {
        short8 vf = *reinterpret_cast<const short8*>(&vl[16 * ct + lr][ks * 32 + lg * 8]);
        o[ct] = __builtin_amdgcn_mfma_f32_16x16x32_bf16(pf, vf, o[ct], 0, 0, 0);
      }
    }
  }

  // epilogue: write unnormalized partials
  const int rowbase = b * 4096 + qt * 64 + 16 * w;
  float* ob = opart + ((size_t)split * 16384 + rowbase) * 64;
  for (int j = 0; j < 4; ++j)
    for (int ct = 0; ct < 4; ++ct)
      ob[(lg * 4 + j) * 64 + 16 * ct + lr] = o[ct][j];
  if (lr == 0) {
    for (int j = 0; j < 4; ++j) {
      int row = rowbase + lg * 4 + j;
      mpart[split * 16384 + row] = m[j];
      lpart[split * 16384 + row] = l[j];
    }
  }
}

__global__ __launch_bounds__(256) void merge_kernel(
    const float* __restrict__ opart, const float* __restrict__ mpart,
    const float* __restrict__ lpart, float* __restrict__ out, int S)
{
  int gid = blockIdx.x * 256 + threadIdx.x;   // 0 .. 16384*64
  int row = gid >> 6;
  int d   = gid & 63;
  float M = -3e38f;
  for (int s = 0; s < S; ++s) M = fmaxf(M, mpart[s * 16384 + row]);
  float denom = 0.f, acc = 0.f;
  for (int s = 0; s < S; ++s) {
    float wgt = __expf(mpart[s * 16384 + row] - M);
    denom += wgt * lpart[s * 16384 + row];
    acc   += wgt * opart[((size_t)s * 16384 + row) * 64 + d];
  }
  out[gid] = acc / denom;
}

// R0 single-pass fallback (used only if ws_size can't hold partials).
__global__ __launch_bounds__(256) void attn_kernel(
    const short* __restrict__ qm, const short* __restrict__ km, const short* __restrict__ vm,
    float* __restrict__ out)
{
  const int b  = blockIdx.x >> 6;
  const int qt = blockIdx.x & 63;
  const int tid = threadIdx.x;
  const int w   = tid >> 6;
  const int lane = tid & 63;
  const int lr  = lane & 15;
  const int lg  = lane >> 4;

  const short* qb = qm + ((size_t)b * 4096 + qt * 64) * 64;
  const short* kb = km + (size_t)b * 4096 * 64;
  const short* vb = vm + (size_t)b * 4096 * 64;

  __shared__ __align__(16) short vl[64][72];
  __shared__ __align__(16) short pl[4][16][72];

  short8 qf[2];
  for (int ks = 0; ks < 2; ++ks)
    qf[ks] = *reinterpret_cast<const short8*>(&qb[(16 * w + lr) * 64 + ks * 32 + lg * 8]);

  float m[4], l[4];
  f32x4 o[4];
  for (int j = 0; j < 4; ++j) { m[j] = -3e38f; l[j] = 0.f; }
  for (int ct = 0; ct < 4; ++ct) o[ct] = (f32x4){0.f, 0.f, 0.f, 0.f};
  const float scale = 0.125f;

  for (int kt = 0; kt < 64; ++kt) {
    __syncthreads();
    const short* vt = vb + (size_t)kt * 64 * 64;
    for (int p = 0; p < 4; ++p) {
      int idx4 = p * 256 + tid;
      int key = idx4 >> 4;
      int d0  = (idx4 & 15) << 2;
      short4v vv = *reinterpret_cast<const short4v*>(&vt[key * 64 + d0]);
      vl[d0 + 0][key] = vv.x;
      vl[d0 + 1][key] = vv.y;
      vl[d0 + 2][key] = vv.z;
      vl[d0 + 3][key] = vv.w;
    }
    f32x4 s[4];
    for (int ct = 0; ct < 4; ++ct) s[ct] = (f32x4){0.f, 0.f, 0.f, 0.f};
    for (int ks = 0; ks < 2; ++ks)
      for (int ct = 0; ct < 4; ++ct) {
        short8 kf = *reinterpret_cast<const short8*>(
            &kb[((size_t)kt * 64 + 16 * ct + lr) * 64 + ks * 32 + lg * 8]);
        s[ct] = __builtin_amdgcn_mfma_f32_16x16x32_bf16(qf[ks], kf, s[ct], 0, 0, 0);
      }
    for (int j = 0; j < 4; ++j) {
      float mx = fmaxf(fmaxf(s[0][j], s[1][j]), fmaxf(s[2][j], s[3][j]));
      for (int off = 1; off < 16; off <<= 1) mx = fmaxf(mx, __shfl_xor(mx, off));
      mx *= scale;
      float mn    = fmaxf(m[j], mx);
      float alpha = __expf(m[j] - mn);
      m[j] = mn;
      float ps = 0.f;
      for (int ct = 0; ct < 4; ++ct) {
        float p = __expf(s[ct][j] * scale - mn);
        ps += p;
        pl[w][lg * 4 + j][16 * ct + lr] = f2bf(p);
      }
      for (int off = 1; off < 16; off <<= 1) ps += __shfl_xor(ps, off);
      l[j] = l[j] * alpha + ps;
      for (int ct = 0; ct < 4; ++ct) o[ct][j] *= alpha;
    }
    __syncthreads();
    for (int ks = 0; ks < 2; ++ks) {
      short8 pf = *reinterpret_cast<const short8*>(&pl[w][lr][ks * 32 + lg * 8]);
      for (int ct = 0; ct < 4; ++ct) {
        short8 vf = *reinterpret_cast<const short8*>(&vl[16 * ct + lr][ks * 32 + lg * 8]);
        o[ct] = __builtin_amdgcn_mfma_f32_16x16x32_bf16(pf, vf, o[ct], 0, 0, 0);
      }
    }
  }
  float* ob = out + ((size_t)b * 4096 + qt * 64 + 16 * w) * 64;
  for (int j = 0; j < 4; ++j) {
    float inv = 1.f / l[j];
    for (int ct = 0; ct < 4; ++ct)
      ob[(lg * 4 + j) * 64 + 16 * ct + lr] = o[ct][j] * inv;
  }
}

extern "C" void kernel_launch(void* const* d_in, const int* in_sizes, int n_in,
                              void* d_out, int out_size, void* d_ws, size_t ws_size,
                              hipStream_t stream) {
  const float* x  = (const float*)d_in[0];
  const float* Wk = (const float*)d_in[1];
  const float* Wq = (const float*)d_in[2];
  const float* Wv = (const float*)d_in[3];

  const size_t MH = (size_t)16384 * 64;   // B*T*H elements
  short* kmat = (short*)d_ws;
  short* qmat = kmat + MH;
  short* vmat = qmat + MH;

  dim3 gproj(16384 / PROJ_BM, 3);
  proj_kernel<<<gproj, 256, 0, stream>>>(x, Wk, Wq, Wv, kmat, qmat, vmat);

  const size_t qkv_bytes  = 3 * MH * sizeof(short);           // 6 MB
  const size_t o_bytes    = MH * sizeof(float);               // 4 MB per split
  const size_t ml_bytes   = 2 * (size_t)16384 * sizeof(float);
  int S = 8;
  while (S > 1 && qkv_bytes + (size_t)S * (o_bytes + ml_bytes) > ws_size) S >>= 1;

  if (qkv_bytes + (size_t)S * (o_bytes + ml_bytes) <= ws_size) {
    float* opart = (float*)((char*)d_ws + qkv_bytes);
    float* mpart = opart + (size_t)S * MH;
    float* lpart = mpart + (size_t)S * 16384;
    attn_split_kernel<<<256 * S, 256, 0, stream>>>(qmat, kmat, vmat,
                                                   opart, mpart, lpart, S, 64 / S);
    merge_kernel<<<4096, 256, 0, stream>>>(opart, mpart, lpart, (float*)d_out, S);
  } else {
    attn_kernel<<<256, 256, 0, stream>>>(qmat, kmat, vmat, (float*)d_out);
  }
}